// Round 1
// baseline (1035.668 us; speedup 1.0000x reference)
//
#include <hip/hip_runtime.h>
#include <math.h>

// GCNII forward: h0 = relu(x @ Wlin + b); 4 x { agg = A@h (CSR gather),
// z = 0.9*agg + 0.1*h0, h = relu((1-beta)z + beta z@Wl) }
//
// Constants for this problem: N=100000, E=1600000, H=128, D=64, L=4.

#define DD 64          // feature dim after lin
#define HH 128         // input hidden
#define SCAN_CHUNK 1024

__global__ __launch_bounds__(256) void zero_i32(int* p, int n) {
    int i = blockIdx.x * blockDim.x + threadIdx.x;
    if (i < n) p[i] = 0;
}

__global__ __launch_bounds__(256) void hist_kernel(const int* __restrict__ row,
                                                   int* __restrict__ cnt, int E) {
    for (int e = blockIdx.x * blockDim.x + threadIdx.x; e < E;
         e += gridDim.x * blockDim.x)
        atomicAdd(&cnt[row[e]], 1);
}

// Phase A: per-block sums (block covers SCAN_CHUNK elements, 256 thr x 4)
__global__ __launch_bounds__(256) void scanA(const int* __restrict__ cnt,
                                             int* __restrict__ bsum, int n) {
    __shared__ int s[256];
    int t = threadIdx.x;
    int base = blockIdx.x * SCAN_CHUNK + t * 4;
    int sum = 0;
#pragma unroll
    for (int i = 0; i < 4; ++i) {
        int idx = base + i;
        if (idx < n) sum += cnt[idx];
    }
    s[t] = sum;
    __syncthreads();
    for (int off = 128; off > 0; off >>= 1) {
        if (t < off) s[t] += s[t + off];
        __syncthreads();
    }
    if (t == 0) bsum[blockIdx.x] = s[0];
}

// Phase B: single-wave exclusive scan of block sums (nb <= 128), writes total
__global__ __launch_bounds__(64) void scanB(int* __restrict__ bsum, int nb,
                                            int* __restrict__ rowptr, int n) {
    int lane = threadIdx.x & 63;
    int i0 = 2 * lane, i1 = 2 * lane + 1;
    int a = (i0 < nb) ? bsum[i0] : 0;
    int b = (i1 < nb) ? bsum[i1] : 0;
    int s = a + b;
    for (int off = 1; off < 64; off <<= 1) {
        int t = __shfl_up(s, off);
        if (lane >= off) s += t;
    }
    int excl = s - (a + b);
    if (i0 < nb) bsum[i0] = excl;
    if (i1 < nb) bsum[i1] = excl + a;
    if (lane == 63) rowptr[n] = s;   // total == E
}

// Phase C: full exclusive scan within block + block offset
__global__ __launch_bounds__(256) void scanC(const int* __restrict__ cnt,
                                             const int* __restrict__ bsum,
                                             int* __restrict__ rowptr, int n) {
    __shared__ int s[256];
    int t = threadIdx.x;
    int base = blockIdx.x * SCAN_CHUNK + t * 4;
    int v[4];
    int sum = 0;
#pragma unroll
    for (int i = 0; i < 4; ++i) {
        int idx = base + i;
        v[i] = (idx < n) ? cnt[idx] : 0;
        sum += v[i];
    }
    s[t] = sum;
    __syncthreads();
    for (int off = 1; off < 256; off <<= 1) {
        int x = (t >= off) ? s[t - off] : 0;
        __syncthreads();
        s[t] += x;
        __syncthreads();
    }
    int excl = (t == 0) ? 0 : s[t - 1];
    excl += bsum[blockIdx.x];
#pragma unroll
    for (int i = 0; i < 4; ++i) {
        int idx = base + i;
        if (idx < n) { rowptr[idx] = excl; excl += v[i]; }
    }
}

__global__ __launch_bounds__(256) void copy_i32(const int* __restrict__ src,
                                                int* __restrict__ dst, int n) {
    int i = blockIdx.x * blockDim.x + threadIdx.x;
    if (i < n) dst[i] = src[i];
}

__global__ __launch_bounds__(256) void scatter_kernel(
    const int* __restrict__ row, const int* __restrict__ col,
    const float* __restrict__ ew, int* __restrict__ fill,
    int* __restrict__ csr_col, float* __restrict__ csr_w, int E) {
    for (int e = blockIdx.x * blockDim.x + threadIdx.x; e < E;
         e += gridDim.x * blockDim.x) {
        int r = row[e];
        int pos = atomicAdd(&fill[r], 1);
        csr_col[pos] = col[e];
        csr_w[pos] = ew[e];
    }
}

// h0 = relu(x @ Wlin + b); writes both x0 and h buffers.
// One wave per node; lane = output feature j. Wlin (128x64 = 32KB) in LDS.
__global__ __launch_bounds__(256) void lin0_kernel(
    const float* __restrict__ x, const float* __restrict__ Wlin,
    const float* __restrict__ b, float* __restrict__ x0,
    float* __restrict__ h, int n) {
    __shared__ float Ws[HH * DD];
    for (int i = threadIdx.x; i < HH * DD; i += blockDim.x) Ws[i] = Wlin[i];
    __syncthreads();
    int wave = threadIdx.x >> 6, lane = threadIdx.x & 63;
    int wpb = blockDim.x >> 6;
    float bias = b[lane];
    for (int node = blockIdx.x * wpb + wave; node < n; node += gridDim.x * wpb) {
        float xa = x[(size_t)node * HH + lane];
        float xb = x[(size_t)node * HH + 64 + lane];
        float acc0 = bias, acc1 = 0.f;
#pragma unroll
        for (int k = 0; k < 64; ++k) {
            float xv = __shfl(xa, k);
            acc0 += xv * Ws[k * DD + lane];
        }
#pragma unroll
        for (int k = 0; k < 64; ++k) {
            float xv = __shfl(xb, k);
            acc1 += xv * Ws[(64 + k) * DD + lane];
        }
        float r = fmaxf(acc0 + acc1, 0.f);
        x0[(size_t)node * DD + lane] = r;
        h[(size_t)node * DD + lane] = r;
    }
}

// One GCNII layer, fused: CSR gather-SpMM + residual mix + 64x64 dense + relu.
// One wave per node; lane = feature dim. W column held in 64 VGPRs.
__global__ __launch_bounds__(256) void layer_kernel(
    const float* __restrict__ h_in, const float* __restrict__ x0,
    const int* __restrict__ rowptr, const int* __restrict__ csr_col,
    const float* __restrict__ csr_w, const float* __restrict__ W,
    float* __restrict__ h_out, float beta, int n) {
    int wave = threadIdx.x >> 6, lane = threadIdx.x & 63;
    int wpb = blockDim.x >> 6;
    float wcol[64];
#pragma unroll
    for (int d = 0; d < 64; ++d) wcol[d] = W[d * DD + lane];

    for (int node = blockIdx.x * wpb + wave; node < n; node += gridDim.x * wpb) {
        int beg = rowptr[node], end = rowptr[node + 1];
        float acc0 = 0.f, acc1 = 0.f;
        int e = beg;
        for (; e + 1 < end; e += 2) {
            int c0 = csr_col[e], c1 = csr_col[e + 1];
            float w0 = csr_w[e], w1 = csr_w[e + 1];
            acc0 += h_in[(size_t)c0 * DD + lane] * w0;
            acc1 += h_in[(size_t)c1 * DD + lane] * w1;
        }
        if (e < end) {
            int c0 = csr_col[e];
            acc0 += h_in[(size_t)c0 * DD + lane] * csr_w[e];
        }
        float z = 0.9f * (acc0 + acc1) + 0.1f * x0[(size_t)node * DD + lane];
        // dot = sum_d z_d * W[d][lane], 4 partial accumulators
        float d0 = 0.f, d1 = 0.f, d2 = 0.f, d3 = 0.f;
#pragma unroll
        for (int d = 0; d < 64; d += 4) {
            d0 += __shfl(z, d + 0) * wcol[d + 0];
            d1 += __shfl(z, d + 1) * wcol[d + 1];
            d2 += __shfl(z, d + 2) * wcol[d + 2];
            d3 += __shfl(z, d + 3) * wcol[d + 3];
        }
        float dot = (d0 + d1) + (d2 + d3);
        float o = (1.f - beta) * z + beta * dot;
        h_out[(size_t)node * DD + lane] = fmaxf(o, 0.f);
    }
}

static inline size_t align256(size_t x) { return (x + 255) & ~(size_t)255; }

extern "C" void kernel_launch(void* const* d_in, const int* in_sizes, int n_in,
                              void* d_out, int out_size, void* d_ws, size_t ws_size,
                              hipStream_t stream) {
    const float* x      = (const float*)d_in[0];
    const int*   row    = (const int*)d_in[1];
    const int*   col    = (const int*)d_in[2];
    const float* ew     = (const float*)d_in[3];
    const float* w_lin  = (const float*)d_in[4];
    const float* b_lin  = (const float*)d_in[5];
    const float* conv_w = (const float*)d_in[6];
    float* out = (float*)d_out;

    const int N = in_sizes[0] / HH;   // 100000
    const int E = in_sizes[1];        // 1600000
    const int L = in_sizes[6] / (DD * DD);  // 4

    // workspace layout
    char* ws = (char*)d_ws;
    size_t off = 0;
    int* cnt = (int*)(ws + off);       off = align256(off + (size_t)N * 4);
    int* rowptr = (int*)(ws + off);    off = align256(off + (size_t)(N + 1) * 4);
    int* fill = (int*)(ws + off);      off = align256(off + (size_t)N * 4);
    int* bsum = (int*)(ws + off);      off = align256(off + 1024 * 4);
    int* csr_col = (int*)(ws + off);   off = align256(off + (size_t)E * 4);
    float* csr_w = (float*)(ws + off); off = align256(off + (size_t)E * 4);
    float* x0 = (float*)(ws + off);    off = align256(off + (size_t)N * DD * 4);
    float* hA = (float*)(ws + off);    off = align256(off + (size_t)N * DD * 4);
    (void)ws_size;

    const int nb = (N + SCAN_CHUNK - 1) / SCAN_CHUNK;

    // ---- CSR build ----
    zero_i32<<<(N + 255) / 256, 256, 0, stream>>>(cnt, N);
    hist_kernel<<<2048, 256, 0, stream>>>(row, cnt, E);
    scanA<<<nb, 256, 0, stream>>>(cnt, bsum, N);
    scanB<<<1, 64, 0, stream>>>(bsum, nb, rowptr, N);
    scanC<<<nb, 256, 0, stream>>>(cnt, bsum, rowptr, N);
    copy_i32<<<(N + 255) / 256, 256, 0, stream>>>(rowptr, fill, N);
    scatter_kernel<<<2048, 256, 0, stream>>>(row, col, ew, fill, csr_col, csr_w, E);

    // ---- h0 = relu(x @ Wlin + b); h lives in d_out first ----
    lin0_kernel<<<2048, 256, 0, stream>>>(x, w_lin, b_lin, x0, out, N);

    // ---- L layers, ping-pong between d_out and hA; ends in d_out (L even) ----
    for (int l = 0; l < L; ++l) {
        float beta = logf(0.5f / (float)(l + 1) + 1.0f);
        const float* hin = (l % 2 == 0) ? out : hA;
        float* hout      = (l % 2 == 0) ? hA : out;
        layer_kernel<<<2048, 256, 0, stream>>>(hin, x0, rowptr, csr_col, csr_w,
                                               conv_w + (size_t)l * DD * DD,
                                               hout, beta, N);
    }
}

// Round 2
// 793.043 us; speedup vs baseline: 1.3059x; 1.3059x over previous
//
#include <hip/hip_runtime.h>
#include <math.h>

// GCNII forward: h0 = relu(x @ Wlin + b); L x { agg = A@h (CSR gather),
// z = 0.9*agg + 0.1*x0, h = relu(z @ W'_l) } with W'_l = (1-beta)I + beta*W_l.
// Constants: N=100000, E=1600000, H=128, D=64, L=4.

#define DD 64
#define HH 128
#define SCAN_CHUNK 1024

__global__ __launch_bounds__(256) void zero_i32(int* p, int n) {
    int i = blockIdx.x * blockDim.x + threadIdx.x;
    if (i < n) p[i] = 0;
}

__global__ __launch_bounds__(256) void hist_kernel(const int* __restrict__ row,
                                                   int* __restrict__ cnt, int E) {
    for (int e = blockIdx.x * blockDim.x + threadIdx.x; e < E;
         e += gridDim.x * blockDim.x)
        atomicAdd(&cnt[row[e]], 1);
}

__global__ __launch_bounds__(256) void scanA(const int* __restrict__ cnt,
                                             int* __restrict__ bsum, int n) {
    __shared__ int s[256];
    int t = threadIdx.x;
    int base = blockIdx.x * SCAN_CHUNK + t * 4;
    int sum = 0;
#pragma unroll
    for (int i = 0; i < 4; ++i) {
        int idx = base + i;
        if (idx < n) sum += cnt[idx];
    }
    s[t] = sum;
    __syncthreads();
    for (int off = 128; off > 0; off >>= 1) {
        if (t < off) s[t] += s[t + off];
        __syncthreads();
    }
    if (t == 0) bsum[blockIdx.x] = s[0];
}

__global__ __launch_bounds__(64) void scanB(int* __restrict__ bsum, int nb,
                                            int* __restrict__ rowptr, int n) {
    int lane = threadIdx.x & 63;
    int i0 = 2 * lane, i1 = 2 * lane + 1;
    int a = (i0 < nb) ? bsum[i0] : 0;
    int b = (i1 < nb) ? bsum[i1] : 0;
    int s = a + b;
    for (int off = 1; off < 64; off <<= 1) {
        int t = __shfl_up(s, off);
        if (lane >= off) s += t;
    }
    int excl = s - (a + b);
    if (i0 < nb) bsum[i0] = excl;
    if (i1 < nb) bsum[i1] = excl + a;
    if (lane == 63) rowptr[n] = s;   // total == E
}

// Full exclusive scan; writes BOTH rowptr and the scatter cursor array.
__global__ __launch_bounds__(256) void scanC(const int* __restrict__ cnt,
                                             const int* __restrict__ bsum,
                                             int* __restrict__ rowptr,
                                             int* __restrict__ fill, int n) {
    __shared__ int s[256];
    int t = threadIdx.x;
    int base = blockIdx.x * SCAN_CHUNK + t * 4;
    int v[4];
    int sum = 0;
#pragma unroll
    for (int i = 0; i < 4; ++i) {
        int idx = base + i;
        v[i] = (idx < n) ? cnt[idx] : 0;
        sum += v[i];
    }
    s[t] = sum;
    __syncthreads();
    for (int off = 1; off < 256; off <<= 1) {
        int x = (t >= off) ? s[t - off] : 0;
        __syncthreads();
        s[t] += x;
        __syncthreads();
    }
    int excl = (t == 0) ? 0 : s[t - 1];
    excl += bsum[blockIdx.x];
#pragma unroll
    for (int i = 0; i < 4; ++i) {
        int idx = base + i;
        if (idx < n) { rowptr[idx] = excl; fill[idx] = excl; excl += v[i]; }
    }
}

// Scatter interleaved {col, weight} records (one 8B store per edge).
__global__ __launch_bounds__(256) void scatter_kernel(
    const int* __restrict__ row, const int* __restrict__ col,
    const float* __restrict__ ew, int* __restrict__ fill,
    int2* __restrict__ cw, int E) {
    for (int e = blockIdx.x * blockDim.x + threadIdx.x; e < E;
         e += gridDim.x * blockDim.x) {
        int r = row[e];
        int pos = atomicAdd(&fill[r], 1);
        cw[pos] = make_int2(col[e], __float_as_int(ew[e]));
    }
}

// W'_l = (1-beta_l) I + beta_l W_l, all L layers at once.
__global__ __launch_bounds__(256) void prep_w(const float* __restrict__ conv_w,
                                              float* __restrict__ Wp, int total) {
    int i = blockIdx.x * blockDim.x + threadIdx.x;
    if (i >= total) return;
    int l = i >> 12;            // / 4096
    int r = i & 4095;
    int d = r >> 6, j = r & 63;
    float beta = logf(0.5f / (float)(l + 1) + 1.0f);
    float v = beta * conv_w[i];
    if (d == j) v += 1.0f - beta;
    Wp[i] = v;
}

// h0 = relu(x @ Wlin + b); writes x0 and h.
__global__ __launch_bounds__(256) void lin0_kernel(
    const float* __restrict__ x, const float* __restrict__ Wlin,
    const float* __restrict__ b, float* __restrict__ x0,
    float* __restrict__ h, int n) {
    __shared__ float Ws[HH * DD];
    for (int i = threadIdx.x; i < HH * DD; i += blockDim.x) Ws[i] = Wlin[i];
    __syncthreads();
    int wave = threadIdx.x >> 6, lane = threadIdx.x & 63;
    int wpb = blockDim.x >> 6;
    float bias = b[lane];
    for (int node = blockIdx.x * wpb + wave; node < n; node += gridDim.x * wpb) {
        float xa = x[(size_t)node * HH + lane];
        float xb = x[(size_t)node * HH + 64 + lane];
        float acc0 = bias, acc1 = 0.f;
#pragma unroll
        for (int k = 0; k < 64; ++k) {
            float xv = __shfl(xa, k);
            acc0 += xv * Ws[k * DD + lane];
        }
#pragma unroll
        for (int k = 0; k < 64; ++k) {
            float xv = __shfl(xb, k);
            acc1 += xv * Ws[(64 + k) * DD + lane];
        }
        float r = fmaxf(acc0 + acc1, 0.f);
        x0[(size_t)node * DD + lane] = r;
        h[(size_t)node * DD + lane] = r;
    }
}

// One fused GCNII layer. One wave per node; lane = feature dim.
// Edge records are cooperatively loaded (64 per coalesced int2 load) into a
// per-wave LDS slot, then broadcast-read -> the gather loop has no memory
// dependency on the index stream; 4 independent gathers in flight per iter.
__global__ __launch_bounds__(256) void layer_kernel(
    const float* __restrict__ h_in, const float* __restrict__ x0,
    const int* __restrict__ rowptr, const int2* __restrict__ cw,
    const float* __restrict__ Wp, float* __restrict__ h_out, int n) {
    __shared__ float Ws[DD * DD];     // 16 KB premixed W'
    __shared__ int2 es[4][64];        // per-wave edge-record slot
    for (int i = threadIdx.x; i < DD * DD; i += blockDim.x) Ws[i] = Wp[i];
    __syncthreads();
    int wave = threadIdx.x >> 6, lane = threadIdx.x & 63;

    for (int node = blockIdx.x * 4 + wave; node < n; node += gridDim.x * 4) {
        int beg = rowptr[node], end = rowptr[node + 1];
        float x0v = x0[(size_t)node * DD + lane];   // issue early
        float a0 = 0.f, a1 = 0.f, a2 = 0.f, a3 = 0.f;
        for (int base = beg; base < end; base += 64) {
            int m = end - base;
            if (m > 64) m = 64;
            if (lane < m) es[wave][lane] = cw[base + lane];
            // same-wave LDS write->read; compiler orders via lgkmcnt
            int k = 0;
            for (; k + 3 < m; k += 4) {
                int2 e0 = es[wave][k + 0];
                int2 e1 = es[wave][k + 1];
                int2 e2 = es[wave][k + 2];
                int2 e3 = es[wave][k + 3];
                a0 += h_in[(size_t)e0.x * DD + lane] * __int_as_float(e0.y);
                a1 += h_in[(size_t)e1.x * DD + lane] * __int_as_float(e1.y);
                a2 += h_in[(size_t)e2.x * DD + lane] * __int_as_float(e2.y);
                a3 += h_in[(size_t)e3.x * DD + lane] * __int_as_float(e3.y);
            }
            for (; k < m; ++k) {
                int2 e0 = es[wave][k];
                a0 += h_in[(size_t)e0.x * DD + lane] * __int_as_float(e0.y);
            }
        }
        float z = 0.9f * ((a0 + a1) + (a2 + a3)) + 0.1f * x0v;
        float d0 = 0.f, d1 = 0.f, d2 = 0.f, d3 = 0.f;
#pragma unroll
        for (int d = 0; d < 64; d += 4) {
            d0 += __shfl(z, d + 0) * Ws[(d + 0) * DD + lane];
            d1 += __shfl(z, d + 1) * Ws[(d + 1) * DD + lane];
            d2 += __shfl(z, d + 2) * Ws[(d + 2) * DD + lane];
            d3 += __shfl(z, d + 3) * Ws[(d + 3) * DD + lane];
        }
        h_out[(size_t)node * DD + lane] = fmaxf((d0 + d1) + (d2 + d3), 0.f);
    }
}

static inline size_t align256(size_t x) { return (x + 255) & ~(size_t)255; }

extern "C" void kernel_launch(void* const* d_in, const int* in_sizes, int n_in,
                              void* d_out, int out_size, void* d_ws, size_t ws_size,
                              hipStream_t stream) {
    const float* x      = (const float*)d_in[0];
    const int*   row    = (const int*)d_in[1];
    const int*   col    = (const int*)d_in[2];
    const float* ew     = (const float*)d_in[3];
    const float* w_lin  = (const float*)d_in[4];
    const float* b_lin  = (const float*)d_in[5];
    const float* conv_w = (const float*)d_in[6];
    float* out = (float*)d_out;

    const int N = in_sizes[0] / HH;          // 100000
    const int E = in_sizes[1];               // 1600000
    const int L = in_sizes[6] / (DD * DD);   // 4

    char* ws = (char*)d_ws;
    size_t off = 0;
    int* cnt = (int*)(ws + off);       off = align256(off + (size_t)N * 4);
    int* rowptr = (int*)(ws + off);    off = align256(off + (size_t)(N + 1) * 4);
    int* fill = (int*)(ws + off);      off = align256(off + (size_t)N * 4);
    int* bsum = (int*)(ws + off);      off = align256(off + 1024 * 4);
    int2* cw = (int2*)(ws + off);      off = align256(off + (size_t)E * 8);
    float* x0 = (float*)(ws + off);    off = align256(off + (size_t)N * DD * 4);
    float* hA = (float*)(ws + off);    off = align256(off + (size_t)N * DD * 4);
    float* Wp = (float*)(ws + off);    off = align256(off + (size_t)L * DD * DD * 4);
    (void)ws_size;

    const int nb = (N + SCAN_CHUNK - 1) / SCAN_CHUNK;

    // ---- CSR build ----
    zero_i32<<<(N + 255) / 256, 256, 0, stream>>>(cnt, N);
    hist_kernel<<<2048, 256, 0, stream>>>(row, cnt, E);
    scanA<<<nb, 256, 0, stream>>>(cnt, bsum, N);
    scanB<<<1, 64, 0, stream>>>(bsum, nb, rowptr, N);
    scanC<<<nb, 256, 0, stream>>>(cnt, bsum, rowptr, fill, N);
    scatter_kernel<<<2048, 256, 0, stream>>>(row, col, ew, fill, cw, E);

    // ---- premixed layer weights ----
    int total = L * DD * DD;
    prep_w<<<(total + 255) / 256, 256, 0, stream>>>(conv_w, Wp, total);

    // ---- h0 = relu(x @ Wlin + b) ----
    lin0_kernel<<<2048, 256, 0, stream>>>(x, w_lin, b_lin, x0, out, N);

    // ---- L layers, ping-pong; ends in d_out (L even) ----
    for (int l = 0; l < L; ++l) {
        const float* hin = (l % 2 == 0) ? out : hA;
        float* hout      = (l % 2 == 0) ? hA : out;
        layer_kernel<<<2048, 256, 0, stream>>>(hin, x0, rowptr, cw,
                                               Wp + (size_t)l * DD * DD,
                                               hout, N);
    }
}

// Round 3
// 511.975 us; speedup vs baseline: 2.0229x; 1.5490x over previous
//
#include <hip/hip_runtime.h>
#include <hip/hip_fp16.h>
#include <math.h>

// GCNII forward, fp16-compressed intermediates:
//   h0 = relu(x @ Wlin + b)                       [lin0: tiled GEMM]
//   per layer l: z = 0.9*(A@h) + 0.1*x0           [gather: CSR, LDS edge stage]
//                h = relu(z @ W'_l)               [dense: tiled GEMM]
//   W'_l = (1-beta_l) I + beta_l W_l (premixed).
// Constants: N=100000, E=1600000, H=128, D=64, L=4.

#define DD 64
#define HH 128
#define SCAN_CHUNK 1024
#define M_TILE 128
#define K_CHUNK 32

__device__ inline float h2f(__half h) { return __half2float(h); }
__device__ inline ushort f2h(float f) { return __half_as_ushort(__float2half(f)); }
__device__ inline float us2f(ushort u) { return __half2float(__ushort_as_half(u)); }

__global__ __launch_bounds__(256) void zero_i32(int* p, int n) {
    int i = blockIdx.x * blockDim.x + threadIdx.x;
    if (i < n) p[i] = 0;
}

__global__ __launch_bounds__(256) void hist_kernel(const int* __restrict__ row,
                                                   int* __restrict__ cnt, int E) {
    for (int e = blockIdx.x * blockDim.x + threadIdx.x; e < E;
         e += gridDim.x * blockDim.x)
        atomicAdd(&cnt[row[e]], 1);
}

__global__ __launch_bounds__(256) void scanA(const int* __restrict__ cnt,
                                             int* __restrict__ bsum, int n) {
    __shared__ int s[256];
    int t = threadIdx.x;
    int base = blockIdx.x * SCAN_CHUNK + t * 4;
    int sum = 0;
#pragma unroll
    for (int i = 0; i < 4; ++i) {
        int idx = base + i;
        if (idx < n) sum += cnt[idx];
    }
    s[t] = sum;
    __syncthreads();
    for (int off = 128; off > 0; off >>= 1) {
        if (t < off) s[t] += s[t + off];
        __syncthreads();
    }
    if (t == 0) bsum[blockIdx.x] = s[0];
}

__global__ __launch_bounds__(64) void scanB(int* __restrict__ bsum, int nb,
                                            int* __restrict__ rowptr, int n) {
    int lane = threadIdx.x & 63;
    int i0 = 2 * lane, i1 = 2 * lane + 1;
    int a = (i0 < nb) ? bsum[i0] : 0;
    int b = (i1 < nb) ? bsum[i1] : 0;
    int s = a + b;
    for (int off = 1; off < 64; off <<= 1) {
        int t = __shfl_up(s, off);
        if (lane >= off) s += t;
    }
    int excl = s - (a + b);
    if (i0 < nb) bsum[i0] = excl;
    if (i1 < nb) bsum[i1] = excl + a;
    if (lane == 63) rowptr[n] = s;   // total == E
}

__global__ __launch_bounds__(256) void scanC(const int* __restrict__ cnt,
                                             const int* __restrict__ bsum,
                                             int* __restrict__ rowptr,
                                             int* __restrict__ fill, int n) {
    __shared__ int s[256];
    int t = threadIdx.x;
    int base = blockIdx.x * SCAN_CHUNK + t * 4;
    int v[4];
    int sum = 0;
#pragma unroll
    for (int i = 0; i < 4; ++i) {
        int idx = base + i;
        v[i] = (idx < n) ? cnt[idx] : 0;
        sum += v[i];
    }
    s[t] = sum;
    __syncthreads();
    for (int off = 1; off < 256; off <<= 1) {
        int x = (t >= off) ? s[t - off] : 0;
        __syncthreads();
        s[t] += x;
        __syncthreads();
    }
    int excl = (t == 0) ? 0 : s[t - 1];
    excl += bsum[blockIdx.x];
#pragma unroll
    for (int i = 0; i < 4; ++i) {
        int idx = base + i;
        if (idx < n) { rowptr[idx] = excl; fill[idx] = excl; excl += v[i]; }
    }
}

__global__ __launch_bounds__(256) void scatter_kernel(
    const int* __restrict__ row, const int* __restrict__ col,
    const float* __restrict__ ew, int* __restrict__ fill,
    int2* __restrict__ cw, int E) {
    for (int e = blockIdx.x * blockDim.x + threadIdx.x; e < E;
         e += gridDim.x * blockDim.x) {
        int r = row[e];
        int pos = atomicAdd(&fill[r], 1);
        cw[pos] = make_int2(col[e], __float_as_int(ew[e]));
    }
}

// W'_l = (1-beta_l) I + beta_l W_l, all L layers at once.
__global__ __launch_bounds__(256) void prep_w(const float* __restrict__ conv_w,
                                              float* __restrict__ Wp, int total) {
    int i = blockIdx.x * blockDim.x + threadIdx.x;
    if (i >= total) return;
    int l = i >> 12;
    int r = i & 4095;
    int d = r >> 6, j = r & 63;
    float beta = logf(0.5f / (float)(l + 1) + 1.0f);
    float v = beta * conv_w[i];
    if (d == j) v += 1.0f - beta;
    Wp[i] = v;
}

// h0 = relu(x @ Wlin + b). Register-tiled GEMM: 128-node tile, thread =
// 8 nodes x 4 outputs. Writes x0 (half) and h (half).
__global__ __launch_bounds__(256) void lin0_kernel(
    const float* __restrict__ x, const float* __restrict__ Wlin,
    const float* __restrict__ b, ushort* __restrict__ x0,
    ushort* __restrict__ h, int n) {
    __shared__ float Ws[HH * DD];              // 32 KB
    __shared__ float xs[K_CHUNK][M_TILE + 4];  // transposed x tile, ~16.9 KB
    for (int i = threadIdx.x; i < HH * DD; i += 256) Ws[i] = Wlin[i];

    int t = threadIdx.x;
    int tm = t >> 4;    // node group (8 nodes)
    int tn = t & 15;    // output group (4 outputs)
    int m0 = blockIdx.x * M_TILE;

    float4 bb = *(const float4*)&b[tn * 4];
    float acc[8][4];
#pragma unroll
    for (int mi = 0; mi < 8; ++mi) {
        acc[mi][0] = bb.x; acc[mi][1] = bb.y; acc[mi][2] = bb.z; acc[mi][3] = bb.w;
    }

    for (int kk = 0; kk < HH; kk += K_CHUNK) {
        __syncthreads();
#pragma unroll
        for (int i = 0; i < 4; ++i) {
            int s = t + i * 256;           // 0..1023
            int node = s >> 3;             // 0..127
            int cpos = (s & 7) * 4;        // 0..28
            int g = m0 + node;
            float4 v = make_float4(0.f, 0.f, 0.f, 0.f);
            if (g < n) v = *(const float4*)&x[(size_t)g * HH + kk + cpos];
            xs[cpos + 0][node] = v.x;
            xs[cpos + 1][node] = v.y;
            xs[cpos + 2][node] = v.z;
            xs[cpos + 3][node] = v.w;
        }
        __syncthreads();
#pragma unroll
        for (int k = 0; k < K_CHUNK; ++k) {
            float4 wv = *(const float4*)&Ws[(kk + k) * DD + tn * 4];
            const float* xr = &xs[k][tm * 8];
            float4 xa = *(const float4*)xr;
            float4 xb = *(const float4*)(xr + 4);
            float xm[8] = {xa.x, xa.y, xa.z, xa.w, xb.x, xb.y, xb.z, xb.w};
            float wj[4] = {wv.x, wv.y, wv.z, wv.w};
#pragma unroll
            for (int mi = 0; mi < 8; ++mi)
#pragma unroll
                for (int j = 0; j < 4; ++j)
                    acc[mi][j] += xm[mi] * wj[j];
        }
    }
#pragma unroll
    for (int mi = 0; mi < 8; ++mi) {
        int node = m0 + tm * 8 + mi;
        if (node >= n) continue;
        ushort4 o;
        o.x = f2h(fmaxf(acc[mi][0], 0.f));
        o.y = f2h(fmaxf(acc[mi][1], 0.f));
        o.z = f2h(fmaxf(acc[mi][2], 0.f));
        o.w = f2h(fmaxf(acc[mi][3], 0.f));
        *(ushort4*)&x0[(size_t)node * DD + tn * 4] = o;
        *(ushort4*)&h[(size_t)node * DD + tn * 4] = o;
    }
}

// Gather/SpMM: z = 0.9*(A@h) + 0.1*x0, all half storage. One wave per node,
// lane = feature. Edge records staged 64-at-a-time in per-wave LDS slot;
// 8 independent gather chains.
__global__ __launch_bounds__(256) void gather_kernel(
    const ushort* __restrict__ h_in, const ushort* __restrict__ x0,
    const int* __restrict__ rowptr, const int2* __restrict__ cw,
    ushort* __restrict__ z, int n) {
    __shared__ int2 es[4][64];
    int wave = threadIdx.x >> 6, lane = threadIdx.x & 63;

    for (int node = blockIdx.x * 4 + wave; node < n; node += gridDim.x * 4) {
        int beg = rowptr[node], end = rowptr[node + 1];
        float x0v = us2f(x0[(size_t)node * DD + lane]);
        float a0 = 0.f, a1 = 0.f, a2 = 0.f, a3 = 0.f;
        float a4 = 0.f, a5 = 0.f, a6 = 0.f, a7 = 0.f;
        for (int base = beg; base < end; base += 64) {
            int m = end - base;
            if (m > 64) m = 64;
            if (lane < m) es[wave][lane] = cw[base + lane];
            int k = 0;
            for (; k + 7 < m; k += 8) {
                int2 e0 = es[wave][k + 0];
                int2 e1 = es[wave][k + 1];
                int2 e2 = es[wave][k + 2];
                int2 e3 = es[wave][k + 3];
                int2 e4 = es[wave][k + 4];
                int2 e5 = es[wave][k + 5];
                int2 e6 = es[wave][k + 6];
                int2 e7 = es[wave][k + 7];
                a0 += us2f(h_in[(size_t)e0.x * DD + lane]) * __int_as_float(e0.y);
                a1 += us2f(h_in[(size_t)e1.x * DD + lane]) * __int_as_float(e1.y);
                a2 += us2f(h_in[(size_t)e2.x * DD + lane]) * __int_as_float(e2.y);
                a3 += us2f(h_in[(size_t)e3.x * DD + lane]) * __int_as_float(e3.y);
                a4 += us2f(h_in[(size_t)e4.x * DD + lane]) * __int_as_float(e4.y);
                a5 += us2f(h_in[(size_t)e5.x * DD + lane]) * __int_as_float(e5.y);
                a6 += us2f(h_in[(size_t)e6.x * DD + lane]) * __int_as_float(e6.y);
                a7 += us2f(h_in[(size_t)e7.x * DD + lane]) * __int_as_float(e7.y);
            }
            for (; k < m; ++k) {
                int2 e0 = es[wave][k];
                a0 += us2f(h_in[(size_t)e0.x * DD + lane]) * __int_as_float(e0.y);
            }
        }
        float zv = 0.9f * (((a0 + a1) + (a2 + a3)) + ((a4 + a5) + (a6 + a7)))
                 + 0.1f * x0v;
        z[(size_t)node * DD + lane] = f2h(zv);
    }
}

// h = relu(z @ W'). Tiled GEMM, K=64. Output: half (intermediate layers) or
// f32 (final layer -> d_out).
__global__ __launch_bounds__(256) void dense_kernel(
    const ushort* __restrict__ zin, const float* __restrict__ Wp,
    ushort* __restrict__ h_half, float* __restrict__ h_f32, int n) {
    __shared__ float Ws[DD * DD];              // 16 KB
    __shared__ float xs[K_CHUNK][M_TILE + 4];  // ~16.9 KB
    for (int i = threadIdx.x; i < DD * DD; i += 256) Ws[i] = Wp[i];

    int t = threadIdx.x;
    int tm = t >> 4, tn = t & 15;
    int m0 = blockIdx.x * M_TILE;

    float acc[8][4];
#pragma unroll
    for (int mi = 0; mi < 8; ++mi)
#pragma unroll
        for (int j = 0; j < 4; ++j) acc[mi][j] = 0.f;

    for (int kk = 0; kk < DD; kk += K_CHUNK) {
        __syncthreads();
#pragma unroll
        for (int i = 0; i < 4; ++i) {
            int s = t + i * 256;
            int node = s >> 3;
            int cpos = (s & 7) * 4;
            int g = m0 + node;
            ushort4 v = make_ushort4(0, 0, 0, 0);
            if (g < n) v = *(const ushort4*)&zin[(size_t)g * DD + kk + cpos];
            xs[cpos + 0][node] = us2f(v.x);
            xs[cpos + 1][node] = us2f(v.y);
            xs[cpos + 2][node] = us2f(v.z);
            xs[cpos + 3][node] = us2f(v.w);
        }
        __syncthreads();
#pragma unroll
        for (int k = 0; k < K_CHUNK; ++k) {
            float4 wv = *(const float4*)&Ws[(kk + k) * DD + tn * 4];
            const float* xr = &xs[k][tm * 8];
            float4 xa = *(const float4*)xr;
            float4 xb = *(const float4*)(xr + 4);
            float xm[8] = {xa.x, xa.y, xa.z, xa.w, xb.x, xb.y, xb.z, xb.w};
            float wj[4] = {wv.x, wv.y, wv.z, wv.w};
#pragma unroll
            for (int mi = 0; mi < 8; ++mi)
#pragma unroll
                for (int j = 0; j < 4; ++j)
                    acc[mi][j] += xm[mi] * wj[j];
        }
    }
#pragma unroll
    for (int mi = 0; mi < 8; ++mi) {
        int node = m0 + tm * 8 + mi;
        if (node >= n) continue;
        float o0 = fmaxf(acc[mi][0], 0.f);
        float o1 = fmaxf(acc[mi][1], 0.f);
        float o2 = fmaxf(acc[mi][2], 0.f);
        float o3 = fmaxf(acc[mi][3], 0.f);
        if (h_f32) {
            *(float4*)&h_f32[(size_t)node * DD + tn * 4] =
                make_float4(o0, o1, o2, o3);
        } else {
            ushort4 o;
            o.x = f2h(o0); o.y = f2h(o1); o.z = f2h(o2); o.w = f2h(o3);
            *(ushort4*)&h_half[(size_t)node * DD + tn * 4] = o;
        }
    }
}

static inline size_t align256(size_t x) { return (x + 255) & ~(size_t)255; }

extern "C" void kernel_launch(void* const* d_in, const int* in_sizes, int n_in,
                              void* d_out, int out_size, void* d_ws, size_t ws_size,
                              hipStream_t stream) {
    const float* x      = (const float*)d_in[0];
    const int*   row    = (const int*)d_in[1];
    const int*   col    = (const int*)d_in[2];
    const float* ew     = (const float*)d_in[3];
    const float* w_lin  = (const float*)d_in[4];
    const float* b_lin  = (const float*)d_in[5];
    const float* conv_w = (const float*)d_in[6];
    float* out = (float*)d_out;

    const int N = in_sizes[0] / HH;          // 100000
    const int E = in_sizes[1];               // 1600000
    const int L = in_sizes[6] / (DD * DD);   // 4

    char* ws = (char*)d_ws;
    size_t off = 0;
    int* cnt = (int*)(ws + off);       off = align256(off + (size_t)N * 4);
    int* rowptr = (int*)(ws + off);    off = align256(off + (size_t)(N + 1) * 4);
    int* fill = (int*)(ws + off);      off = align256(off + (size_t)N * 4);
    int* bsum = (int*)(ws + off);      off = align256(off + 1024 * 4);
    int2* cw = (int2*)(ws + off);      off = align256(off + (size_t)E * 8);
    ushort* x0 = (ushort*)(ws + off);  off = align256(off + (size_t)N * DD * 2);
    ushort* hA = (ushort*)(ws + off);  off = align256(off + (size_t)N * DD * 2);
    ushort* hB = (ushort*)(ws + off);  off = align256(off + (size_t)N * DD * 2);
    ushort* zb = (ushort*)(ws + off);  off = align256(off + (size_t)N * DD * 2);
    float* Wp = (float*)(ws + off);    off = align256(off + (size_t)L * DD * DD * 4);
    (void)ws_size;

    const int nb = (N + SCAN_CHUNK - 1) / SCAN_CHUNK;
    const int mt = (N + M_TILE - 1) / M_TILE;

    // ---- CSR build ----
    zero_i32<<<(N + 255) / 256, 256, 0, stream>>>(cnt, N);
    hist_kernel<<<2048, 256, 0, stream>>>(row, cnt, E);
    scanA<<<nb, 256, 0, stream>>>(cnt, bsum, N);
    scanB<<<1, 64, 0, stream>>>(bsum, nb, rowptr, N);
    scanC<<<nb, 256, 0, stream>>>(cnt, bsum, rowptr, fill, N);
    scatter_kernel<<<2048, 256, 0, stream>>>(row, col, ew, fill, cw, E);

    // ---- premixed layer weights ----
    int total = L * DD * DD;
    prep_w<<<(total + 255) / 256, 256, 0, stream>>>(conv_w, Wp, total);

    // ---- h0 = relu(x @ Wlin + b) -> x0, hA (half) ----
    lin0_kernel<<<mt, 256, 0, stream>>>(x, w_lin, b_lin, x0, hA, N);

    // ---- L layers: gather -> dense; ping-pong hA/hB; final layer -> f32 out
    for (int l = 0; l < L; ++l) {
        const ushort* hin = (l % 2 == 0) ? hA : hB;
        ushort* hout      = (l % 2 == 0) ? hB : hA;
        gather_kernel<<<2048, 256, 0, stream>>>(hin, x0, rowptr, cw, zb, N);
        bool last = (l == L - 1);
        dense_kernel<<<mt, 256, 0, stream>>>(zb, Wp + (size_t)l * DD * DD,
                                             last ? nullptr : hout,
                                             last ? out : nullptr, N);
    }
}

// Round 4
// 429.450 us; speedup vs baseline: 2.4116x; 1.1922x over previous
//
#include <hip/hip_runtime.h>
#include <hip/hip_fp16.h>
#include <math.h>

// GCNII forward, fp16-compressed intermediates:
//   h0 = relu(x @ Wlin + b)                       [lin0: tiled GEMM]
//   per layer l: z = 0.9*(A@h) + 0.1*x0           [gather: CSR, 4-edge/instr]
//                h = relu(z @ W'_l)               [dense: tiled GEMM]
//   W'_l = (1-beta_l) I + beta_l W_l (premixed).
// CSR build uses destination-bucketed, XCD-affine scatter: block group
// (blockIdx&7) owns node range [N*g/8, N*(g+1)/8) so cw/fill/cnt lines are
// written by exactly one XCD's L2 (kills the 8x write amplification seen as
// WRITE_SIZE=100MB for a 12.8MB buffer).
// Constants: N=100000, E=1600000, H=128, D=64, L=4.

#define DD 64
#define HH 128
#define SCAN_CHUNK 1024
#define M_TILE 128
#define K_CHUNK 32

__device__ inline ushort f2h(float f) { return __half_as_ushort(__float2half(f)); }
__device__ inline float us2f(ushort u) { return __half2float(__ushort_as_half(u)); }

__global__ __launch_bounds__(256) void zero_i32(int* p, int n) {
    int i = blockIdx.x * blockDim.x + threadIdx.x;
    if (i < n) p[i] = 0;
}

// Histogram, XCD-affine: group g counts only rows in its node range.
__global__ __launch_bounds__(256) void hist_kernel(const int* __restrict__ row,
                                                   int* __restrict__ cnt,
                                                   int E, int N) {
    int grp = blockIdx.x & 7;
    int bid = blockIdx.x >> 3;
    int nblk = gridDim.x >> 3;
    int lo = (int)((long long)N * grp / 8);
    int hi = (int)((long long)N * (grp + 1) / 8);
    for (int e = bid * blockDim.x + threadIdx.x; e < E; e += nblk * blockDim.x) {
        int r = row[e];
        if (r >= lo && r < hi) atomicAdd(&cnt[r], 1);
    }
}

__global__ __launch_bounds__(256) void scanA(const int* __restrict__ cnt,
                                             int* __restrict__ bsum, int n) {
    __shared__ int s[256];
    int t = threadIdx.x;
    int base = blockIdx.x * SCAN_CHUNK + t * 4;
    int sum = 0;
#pragma unroll
    for (int i = 0; i < 4; ++i) {
        int idx = base + i;
        if (idx < n) sum += cnt[idx];
    }
    s[t] = sum;
    __syncthreads();
    for (int off = 128; off > 0; off >>= 1) {
        if (t < off) s[t] += s[t + off];
        __syncthreads();
    }
    if (t == 0) bsum[blockIdx.x] = s[0];
}

__global__ __launch_bounds__(64) void scanB(int* __restrict__ bsum, int nb,
                                            int* __restrict__ rowptr, int n) {
    int lane = threadIdx.x & 63;
    int i0 = 2 * lane, i1 = 2 * lane + 1;
    int a = (i0 < nb) ? bsum[i0] : 0;
    int b = (i1 < nb) ? bsum[i1] : 0;
    int s = a + b;
    for (int off = 1; off < 64; off <<= 1) {
        int t = __shfl_up(s, off);
        if (lane >= off) s += t;
    }
    int excl = s - (a + b);
    if (i0 < nb) bsum[i0] = excl;
    if (i1 < nb) bsum[i1] = excl + a;
    if (lane == 63) rowptr[n] = s;   // total == E
}

__global__ __launch_bounds__(256) void scanC(const int* __restrict__ cnt,
                                             const int* __restrict__ bsum,
                                             int* __restrict__ rowptr,
                                             int* __restrict__ fill, int n) {
    __shared__ int s[256];
    int t = threadIdx.x;
    int base = blockIdx.x * SCAN_CHUNK + t * 4;
    int v[4];
    int sum = 0;
#pragma unroll
    for (int i = 0; i < 4; ++i) {
        int idx = base + i;
        v[i] = (idx < n) ? cnt[idx] : 0;
        sum += v[i];
    }
    s[t] = sum;
    __syncthreads();
    for (int off = 1; off < 256; off <<= 1) {
        int x = (t >= off) ? s[t - off] : 0;
        __syncthreads();
        s[t] += x;
        __syncthreads();
    }
    int excl = (t == 0) ? 0 : s[t - 1];
    excl += bsum[blockIdx.x];
#pragma unroll
    for (int i = 0; i < 4; ++i) {
        int idx = base + i;
        if (idx < n) { rowptr[idx] = excl; fill[idx] = excl; excl += v[i]; }
    }
}

// Scatter {col, weight} records, XCD-affine by destination range.
__global__ __launch_bounds__(256) void scatter_kernel(
    const int* __restrict__ row, const int* __restrict__ col,
    const float* __restrict__ ew, int* __restrict__ fill,
    int2* __restrict__ cw, int E, int N) {
    int grp = blockIdx.x & 7;
    int bid = blockIdx.x >> 3;
    int nblk = gridDim.x >> 3;
    int lo = (int)((long long)N * grp / 8);
    int hi = (int)((long long)N * (grp + 1) / 8);
    for (int e = bid * blockDim.x + threadIdx.x; e < E; e += nblk * blockDim.x) {
        int r = row[e];
        if (r >= lo && r < hi) {
            int pos = atomicAdd(&fill[r], 1);
            cw[pos] = make_int2(col[e], __float_as_int(ew[e]));
        }
    }
}

// W'_l = (1-beta_l) I + beta_l W_l, all L layers at once.
__global__ __launch_bounds__(256) void prep_w(const float* __restrict__ conv_w,
                                              float* __restrict__ Wp, int total) {
    int i = blockIdx.x * blockDim.x + threadIdx.x;
    if (i >= total) return;
    int l = i >> 12;
    int r = i & 4095;
    int d = r >> 6, j = r & 63;
    float beta = logf(0.5f / (float)(l + 1) + 1.0f);
    float v = beta * conv_w[i];
    if (d == j) v += 1.0f - beta;
    Wp[i] = v;
}

// h0 = relu(x @ Wlin + b). Register-tiled GEMM. Writes x0, h (half).
__global__ __launch_bounds__(256) void lin0_kernel(
    const float* __restrict__ x, const float* __restrict__ Wlin,
    const float* __restrict__ b, ushort* __restrict__ x0,
    ushort* __restrict__ h, int n) {
    __shared__ float Ws[HH * DD];              // 32 KB
    __shared__ float xs[K_CHUNK][M_TILE + 4];
    for (int i = threadIdx.x; i < HH * DD; i += 256) Ws[i] = Wlin[i];

    int t = threadIdx.x;
    int tm = t >> 4, tn = t & 15;
    int m0 = blockIdx.x * M_TILE;

    float4 bb = *(const float4*)&b[tn * 4];
    float acc[8][4];
#pragma unroll
    for (int mi = 0; mi < 8; ++mi) {
        acc[mi][0] = bb.x; acc[mi][1] = bb.y; acc[mi][2] = bb.z; acc[mi][3] = bb.w;
    }

    for (int kk = 0; kk < HH; kk += K_CHUNK) {
        __syncthreads();
#pragma unroll
        for (int i = 0; i < 4; ++i) {
            int s = t + i * 256;
            int node = s >> 3;
            int cpos = (s & 7) * 4;
            int g = m0 + node;
            float4 v = make_float4(0.f, 0.f, 0.f, 0.f);
            if (g < n) v = *(const float4*)&x[(size_t)g * HH + kk + cpos];
            xs[cpos + 0][node] = v.x;
            xs[cpos + 1][node] = v.y;
            xs[cpos + 2][node] = v.z;
            xs[cpos + 3][node] = v.w;
        }
        __syncthreads();
#pragma unroll
        for (int k = 0; k < K_CHUNK; ++k) {
            float4 wv = *(const float4*)&Ws[(kk + k) * DD + tn * 4];
            const float* xr = &xs[k][tm * 8];
            float4 xa = *(const float4*)xr;
            float4 xb = *(const float4*)(xr + 4);
            float xm[8] = {xa.x, xa.y, xa.z, xa.w, xb.x, xb.y, xb.z, xb.w};
            float wj[4] = {wv.x, wv.y, wv.z, wv.w};
#pragma unroll
            for (int mi = 0; mi < 8; ++mi)
#pragma unroll
                for (int j = 0; j < 4; ++j)
                    acc[mi][j] += xm[mi] * wj[j];
        }
    }
#pragma unroll
    for (int mi = 0; mi < 8; ++mi) {
        int node = m0 + tm * 8 + mi;
        if (node >= n) continue;
        ushort4 o;
        o.x = f2h(fmaxf(acc[mi][0], 0.f));
        o.y = f2h(fmaxf(acc[mi][1], 0.f));
        o.z = f2h(fmaxf(acc[mi][2], 0.f));
        o.w = f2h(fmaxf(acc[mi][3], 0.f));
        *(ushort4*)&x0[(size_t)node * DD + tn * 4] = o;
        *(ushort4*)&h[(size_t)node * DD + tn * 4] = o;
    }
}

// Gather/SpMM: z = 0.9*(A@h) + 0.1*x0 (half storage). One wave per node.
// Packed gather: 16 lanes x 8B cover one 128B h row -> one vmem instruction
// gathers 4 edges (4 independent chains/iter). Masked tail via weight=0.
// Final cross-group combine: 2 shfl_xor rounds.
__global__ __launch_bounds__(256) void gather_kernel(
    const ushort* __restrict__ h_in, const ushort* __restrict__ x0,
    const int* __restrict__ rowptr, const int2* __restrict__ cw,
    ushort* __restrict__ z, int n) {
    __shared__ int2 es[4][64];
    int wave = threadIdx.x >> 6, lane = threadIdx.x & 63;
    int grp = lane >> 4, sub = lane & 15;

    for (int node = blockIdx.x * 4 + wave; node < n; node += gridDim.x * 4) {
        int beg = rowptr[node], end = rowptr[node + 1];
        uint2 x0v = *(const uint2*)&x0[(size_t)node * DD + sub * 4];
        float a0 = 0.f, a1 = 0.f, a2 = 0.f, a3 = 0.f;
        for (int base = beg; base < end; base += 64) {
            int m = end - base;
            if (m > 64) m = 64;
            if (lane < m) es[wave][lane] = cw[base + lane];
            for (int k = 0; k < m; k += 16) {
#pragma unroll
                for (int q = 0; q < 4; ++q) {      // 4 independent gathers
                    int idx = k + q * 4 + grp;
                    bool vld = idx < m;
                    int cidx = vld ? idx : (m - 1);
                    int2 r = es[wave][cidx];
                    float w = vld ? __int_as_float(r.y) : 0.f;
                    uint2 hv = *(const uint2*)&h_in[(size_t)r.x * DD + sub * 4];
                    a0 += w * us2f((ushort)(hv.x & 0xffff));
                    a1 += w * us2f((ushort)(hv.x >> 16));
                    a2 += w * us2f((ushort)(hv.y & 0xffff));
                    a3 += w * us2f((ushort)(hv.y >> 16));
                }
            }
        }
        // combine the 4 groups (each holds partial sums for same features)
        a0 += __shfl_xor(a0, 16); a0 += __shfl_xor(a0, 32);
        a1 += __shfl_xor(a1, 16); a1 += __shfl_xor(a1, 32);
        a2 += __shfl_xor(a2, 16); a2 += __shfl_xor(a2, 32);
        a3 += __shfl_xor(a3, 16); a3 += __shfl_xor(a3, 32);
        if (lane < 16) {
            float z0 = 0.9f * a0 + 0.1f * us2f((ushort)(x0v.x & 0xffff));
            float z1 = 0.9f * a1 + 0.1f * us2f((ushort)(x0v.x >> 16));
            float z2 = 0.9f * a2 + 0.1f * us2f((ushort)(x0v.y & 0xffff));
            float z3 = 0.9f * a3 + 0.1f * us2f((ushort)(x0v.y >> 16));
            uint zlo = (uint)f2h(z0) | ((uint)f2h(z1) << 16);
            uint zhi = (uint)f2h(z2) | ((uint)f2h(z3) << 16);
            *(uint2*)&z[(size_t)node * DD + sub * 4] = make_uint2(zlo, zhi);
        }
    }
}

// h = relu(z @ W'). Tiled GEMM, K=64. Output: half or f32 (final layer).
__global__ __launch_bounds__(256) void dense_kernel(
    const ushort* __restrict__ zin, const float* __restrict__ Wp,
    ushort* __restrict__ h_half, float* __restrict__ h_f32, int n) {
    __shared__ float Ws[DD * DD];
    __shared__ float xs[K_CHUNK][M_TILE + 4];
    for (int i = threadIdx.x; i < DD * DD; i += 256) Ws[i] = Wp[i];

    int t = threadIdx.x;
    int tm = t >> 4, tn = t & 15;
    int m0 = blockIdx.x * M_TILE;

    float acc[8][4];
#pragma unroll
    for (int mi = 0; mi < 8; ++mi)
#pragma unroll
        for (int j = 0; j < 4; ++j) acc[mi][j] = 0.f;

    for (int kk = 0; kk < DD; kk += K_CHUNK) {
        __syncthreads();
#pragma unroll
        for (int i = 0; i < 4; ++i) {
            int s = t + i * 256;
            int node = s >> 3;
            int cpos = (s & 7) * 4;
            int g = m0 + node;
            ushort4 v = make_ushort4(0, 0, 0, 0);
            if (g < n) v = *(const ushort4*)&zin[(size_t)g * DD + kk + cpos];
            xs[cpos + 0][node] = us2f(v.x);
            xs[cpos + 1][node] = us2f(v.y);
            xs[cpos + 2][node] = us2f(v.z);
            xs[cpos + 3][node] = us2f(v.w);
        }
        __syncthreads();
#pragma unroll
        for (int k = 0; k < K_CHUNK; ++k) {
            float4 wv = *(const float4*)&Ws[(kk + k) * DD + tn * 4];
            const float* xr = &xs[k][tm * 8];
            float4 xa = *(const float4*)xr;
            float4 xb = *(const float4*)(xr + 4);
            float xm[8] = {xa.x, xa.y, xa.z, xa.w, xb.x, xb.y, xb.z, xb.w};
            float wj[4] = {wv.x, wv.y, wv.z, wv.w};
#pragma unroll
            for (int mi = 0; mi < 8; ++mi)
#pragma unroll
                for (int j = 0; j < 4; ++j)
                    acc[mi][j] += xm[mi] * wj[j];
        }
    }
#pragma unroll
    for (int mi = 0; mi < 8; ++mi) {
        int node = m0 + tm * 8 + mi;
        if (node >= n) continue;
        float o0 = fmaxf(acc[mi][0], 0.f);
        float o1 = fmaxf(acc[mi][1], 0.f);
        float o2 = fmaxf(acc[mi][2], 0.f);
        float o3 = fmaxf(acc[mi][3], 0.f);
        if (h_f32) {
            *(float4*)&h_f32[(size_t)node * DD + tn * 4] =
                make_float4(o0, o1, o2, o3);
        } else {
            ushort4 o;
            o.x = f2h(o0); o.y = f2h(o1); o.z = f2h(o2); o.w = f2h(o3);
            *(ushort4*)&h_half[(size_t)node * DD + tn * 4] = o;
        }
    }
}

static inline size_t align256(size_t x) { return (x + 255) & ~(size_t)255; }

extern "C" void kernel_launch(void* const* d_in, const int* in_sizes, int n_in,
                              void* d_out, int out_size, void* d_ws, size_t ws_size,
                              hipStream_t stream) {
    const float* x      = (const float*)d_in[0];
    const int*   row    = (const int*)d_in[1];
    const int*   col    = (const int*)d_in[2];
    const float* ew     = (const float*)d_in[3];
    const float* w_lin  = (const float*)d_in[4];
    const float* b_lin  = (const float*)d_in[5];
    const float* conv_w = (const float*)d_in[6];
    float* out = (float*)d_out;

    const int N = in_sizes[0] / HH;          // 100000
    const int E = in_sizes[1];               // 1600000
    const int L = in_sizes[6] / (DD * DD);   // 4

    char* ws = (char*)d_ws;
    size_t off = 0;
    int* cnt = (int*)(ws + off);       off = align256(off + (size_t)N * 4);
    int* rowptr = (int*)(ws + off);    off = align256(off + (size_t)(N + 1) * 4);
    int* fill = (int*)(ws + off);      off = align256(off + (size_t)N * 4);
    int* bsum = (int*)(ws + off);      off = align256(off + 1024 * 4);
    int2* cw = (int2*)(ws + off);      off = align256(off + (size_t)E * 8);
    ushort* x0 = (ushort*)(ws + off);  off = align256(off + (size_t)N * DD * 2);
    ushort* hA = (ushort*)(ws + off);  off = align256(off + (size_t)N * DD * 2);
    ushort* hB = (ushort*)(ws + off);  off = align256(off + (size_t)N * DD * 2);
    ushort* zb = (ushort*)(ws + off);  off = align256(off + (size_t)N * DD * 2);
    float* Wp = (float*)(ws + off);    off = align256(off + (size_t)L * DD * DD * 4);
    (void)ws_size;

    const int nb = (N + SCAN_CHUNK - 1) / SCAN_CHUNK;
    const int mt = (N + M_TILE - 1) / M_TILE;

    // ---- CSR build (XCD-affine hist + scatter) ----
    zero_i32<<<(N + 255) / 256, 256, 0, stream>>>(cnt, N);
    hist_kernel<<<2048, 256, 0, stream>>>(row, cnt, E, N);
    scanA<<<nb, 256, 0, stream>>>(cnt, bsum, N);
    scanB<<<1, 64, 0, stream>>>(bsum, nb, rowptr, N);
    scanC<<<nb, 256, 0, stream>>>(cnt, bsum, rowptr, fill, N);
    scatter_kernel<<<2048, 256, 0, stream>>>(row, col, ew, fill, cw, E, N);

    // ---- premixed layer weights ----
    int total = L * DD * DD;
    prep_w<<<(total + 255) / 256, 256, 0, stream>>>(conv_w, Wp, total);

    // ---- h0 = relu(x @ Wlin + b) -> x0, hA (half) ----
    lin0_kernel<<<mt, 256, 0, stream>>>(x, w_lin, b_lin, x0, hA, N);

    // ---- L layers: gather -> dense; ping-pong hA/hB; final -> f32 out ----
    for (int l = 0; l < L; ++l) {
        const ushort* hin = (l % 2 == 0) ? hA : hB;
        ushort* hout      = (l % 2 == 0) ? hB : hA;
        gather_kernel<<<2048, 256, 0, stream>>>(hin, x0, rowptr, cw, zb, N);
        bool last = (l == L - 1);
        dense_kernel<<<mt, 256, 0, stream>>>(zb, Wp + (size_t)l * DD * DD,
                                             last ? nullptr : hout,
                                             last ? out : nullptr, N);
    }
}